// Round 7
// baseline (167.968 us; speedup 1.0000x reference)
//
#include <hip/hip_runtime.h>
#include <hip/hip_bf16.h>

// ---------------------------------------------------------------------------
// GCN layer: out = D^{-1/2} (A_set + I) D^{-1/2} @ (x @ W) + bias
// Pipeline (4 dispatches):
//   memset mask+degcnt (8MB+32KB, contiguous)
//   fused_front: [build_adj (atomicOr bitmask + degcnt via old-value test)
//                 | cast x->bf16 | transpose W | zero Hs pad row]
//     - cross-workgroup writes MUST be atomics (round-4 lesson)
//     - degcnt[i] = #distinct neighbors, counted at insertion: removes the
//       gemm->build_ell serial dependency on dinv
//   fused_mid: [gemm 64x64 MFMA: Hs = bf16(dinv[m]*(x@W)), dinv from degcnt
//               | build_ell: mask -> ELL list (stride 128) + zero-row pads]
//     - block-range fused: ell (memory-bound) overlaps gemm (MFMA-bound)
//   spmm: D-split (grid.y=2 halves, 4MB hot set = L2-resident per half);
//     wave gathers 2 neighbors/iter (half-wave each, 16B/lane), shfl_xor(32)
//     cross-half reduce; out[i] = dinv_i*(Hs_i + sum_j Hs_j) + bias
// ---------------------------------------------------------------------------

#define ELL_STRIDE 128

typedef __attribute__((ext_vector_type(8))) short bf16x8;
typedef __attribute__((ext_vector_type(4))) float f32x4;

__device__ __forceinline__ unsigned short f2bf(float f) {
  unsigned u = __float_as_uint(f);
  u = (u + 0x7fff + ((u >> 16) & 1)) >> 16;  // RNE
  return (unsigned short)u;
}
__device__ __forceinline__ float bflo(unsigned u) {
  return __uint_as_float(u << 16);
}
__device__ __forceinline__ float bfhi(unsigned u) {
  return __uint_as_float(u & 0xffff0000u);
}

// ---- fused front-end:
// [0,eb): build_adj  [eb,eb+cb): cast  [..+tb): transpose  [last]: zero pad row
__global__ __launch_bounds__(256) void fused_front_kernel(
    const int* __restrict__ ei, unsigned* __restrict__ mask,
    int* __restrict__ degcnt, int n_edges, int words,
    const float* __restrict__ x, unsigned short* __restrict__ xb, int n4,
    const float* __restrict__ W, unsigned short* __restrict__ Wt, int K, int N,
    unsigned short* __restrict__ Hs, int n_nodes,
    int edge_blocks, int cast_blocks, int tr_blocks) {
  const int bid = blockIdx.x;
  if (bid < edge_blocks) {
    const int e = bid * 256 + threadIdx.x;
    if (e < n_edges) {
      const int u = ei[e];
      const int v = ei[e + n_edges];
      const unsigned bv = 1u << (v & 31);
      const unsigned bu = 1u << (u & 31);
      const unsigned o0 = atomicOr(&mask[(size_t)u * words + (v >> 5)], bv);
      if (!(o0 & bv)) atomicAdd(&degcnt[u], 1);
      const unsigned o1 = atomicOr(&mask[(size_t)v * words + (u >> 5)], bu);
      if (!(o1 & bu)) atomicAdd(&degcnt[v], 1);
    }
    return;
  }
  if (bid < edge_blocks + cast_blocks) {
    const int t = (bid - edge_blocks) * 256 + threadIdx.x;
    if (t < n4) {
      float4 v = ((const float4*)x)[t];
      ushort4 o;
      o.x = f2bf(v.x); o.y = f2bf(v.y); o.z = f2bf(v.z); o.w = f2bf(v.w);
      ((ushort4*)xb)[t] = o;
    }
    return;
  }
  if (bid < edge_blocks + cast_blocks + tr_blocks) {
    // transpose+cast: W[K][N] fp32 -> Wt[N][K] bf16, 32x32 tiles
    __shared__ float tile[32][33];
    const int b = bid - edge_blocks - cast_blocks;
    const int bx = b & ((N >> 5) - 1);
    const int by = b >> (31 - __builtin_clz(N >> 5));
    const int tx = threadIdx.x & 31;
    const int ty = threadIdx.x >> 5;  // 0..7
#pragma unroll
    for (int r = 0; r < 4; ++r)
      tile[ty + 8 * r][tx] = W[(size_t)(by * 32 + ty + 8 * r) * N + bx * 32 + tx];
    __syncthreads();
#pragma unroll
    for (int r = 0; r < 4; ++r)
      Wt[(size_t)(bx * 32 + ty + 8 * r) * K + by * 32 + tx] =
          f2bf(tile[tx][ty + 8 * r]);
    return;
  }
  // zero the ELL pad row Hs[n_nodes][:]  (N bf16 = N/2 uints; N=512 -> 256)
  {
    const int t = threadIdx.x;
    if (t < (N >> 1)) ((unsigned*)(Hs + (size_t)n_nodes * N))[t] = 0;
  }
}

// ---- fused mid: [0,gb): gemm 64x64   [gb,gb+n/4): build_ell (wave per node)
__global__ __launch_bounds__(256) void fused_mid_kernel(
    const unsigned short* __restrict__ xb,  // [M][K] bf16
    const unsigned short* __restrict__ Wt,  // [N][K] bf16
    const int* __restrict__ degcnt,
    unsigned short* __restrict__ Hs,        // [M+1][N] bf16
    const unsigned* __restrict__ mask, unsigned short* __restrict__ ell,
    int M, int N, int K, int words, int gemm_blocks, int nbx_sh) {
  __shared__ unsigned short As[256 * 8];
  __shared__ unsigned short Bs[256 * 8];

  const int tid = threadIdx.x;
  const int bid = blockIdx.x;

  if (bid < gemm_blocks) {
    const int wave = tid >> 6;
    const int lane = tid & 63;
    const int q = lane >> 4;   // quad
    const int c = lane & 15;
    const int bx = bid & ((1 << nbx_sh) - 1);
    const int by = bid >> nbx_sh;
    const int m0 = by * 64;
    const int n0 = bx * 64;
    const int wr = wave >> 1, wc = wave & 1;

    f32x4 acc[2][2] = {};

    for (int k0 = 0; k0 < K; k0 += 32) {
      {
        const unsigned short* g =
            xb + (size_t)(m0 + lane) * K + k0 + wave * 8;  // kc=wave, row=lane
        __builtin_amdgcn_global_load_lds(
            (const __attribute__((address_space(1))) void*)g,
            (__attribute__((address_space(3))) void*)(As + wave * 64 * 8), 16, 0, 0);
      }
      {
        const int s = tid;  // B: n = s>>2, kc = s&3
        const unsigned short* g =
            Wt + (size_t)(n0 + (s >> 2)) * K + k0 + (s & 3) * 8;
        __builtin_amdgcn_global_load_lds(
            (const __attribute__((address_space(1))) void*)g,
            (__attribute__((address_space(3))) void*)(Bs + wave * 64 * 8), 16, 0, 0);
      }
      __syncthreads();

      bf16x8 a[2], b[2];
#pragma unroll
      for (int tm = 0; tm < 2; ++tm) {
        const int row = wr * 32 + tm * 16 + c;
        a[tm] = *(const bf16x8*)(As + (q * 64 + row) * 8);
      }
#pragma unroll
      for (int tn = 0; tn < 2; ++tn) {
        const int n = wc * 32 + tn * 16 + c;
        b[tn] = *(const bf16x8*)(Bs + (n * 4 + q) * 8);
      }
#pragma unroll
      for (int tm = 0; tm < 2; ++tm)
#pragma unroll
        for (int tn = 0; tn < 2; ++tn)
          acc[tm][tn] = __builtin_amdgcn_mfma_f32_16x16x32_bf16(
              a[tm], b[tn], acc[tm][tn], 0, 0, 0);
      __syncthreads();
    }

    // C/D mapping: col=lane&15, row=quad*4+reg ; dinv from degcnt
#pragma unroll
    for (int tm = 0; tm < 2; ++tm) {
#pragma unroll
      for (int r = 0; r < 4; ++r) {
        const int grow = m0 + wr * 32 + tm * 16 + q * 4 + r;
        const float di = rsqrtf((float)degcnt[grow] + 1.0f);
#pragma unroll
        for (int tn = 0; tn < 2; ++tn) {
          const int gcol = n0 + wc * 32 + tn * 16 + c;
          Hs[(size_t)grow * N + gcol] = f2bf(di * acc[tm][tn][r]);
        }
      }
    }
    return;
  }

  // ---- build_ell: one wave per node, popcount + lane prefix-scan
  {
    const int wave = tid >> 6, lane = tid & 63;
    const int node = (bid - gemm_blocks) * 4 + wave;
    const unsigned* __restrict__ row = mask + (size_t)node * words;
    unsigned short* __restrict__ out = ell + (size_t)node * ELL_STRIDE;

    int running = 0;
    for (int r = 0; r < words; r += 64) {
      const int w = r + lane;
      unsigned bits = row[w];
      const int cnt = __popc(bits);
      int x = cnt;
#pragma unroll
      for (int d = 1; d < 64; d <<= 1) {
        int y = __shfl_up(x, d, 64);
        if (lane >= d) x += y;
      }
      int pos = running + x - cnt;
      while (bits) {
        const int b = __builtin_ctz(bits);
        bits &= bits - 1;
        if (pos < ELL_STRIDE) out[pos] = (unsigned short)((w << 5) + b);
        ++pos;
      }
      running += __shfl(x, 63, 64);
    }
    // pad up to even count with the zero row (index M) for the pair-gather
    if (lane == 0) {
      if (running < ELL_STRIDE) out[running] = (unsigned short)M;
      if (running + 1 < ELL_STRIDE) out[running + 1] = (unsigned short)M;
    }
  }
}

// ---- spmm: grid (n/4, 2). Half h covers columns [h*D/2, (h+1)*D/2).
// Wave = one node; half-wave per neighbor (2 neighbors/iter, 16B/lane);
// cross-half shfl_xor(32) reduce. Per-half hot set = 4MB -> L2-resident.
__global__ __launch_bounds__(256) void spmm_kernel(
    const unsigned short* __restrict__ ell, const int* __restrict__ degcnt,
    const unsigned short* __restrict__ Hs, const float* __restrict__ bias,
    float* __restrict__ out, int n, int D) {
  __shared__ unsigned short jl[4][ELL_STRIDE];
  const int wave = threadIdx.x >> 6, lane = threadIdx.x & 63;
  const int i = blockIdx.x * 4 + wave;  // n divisible by 4
  const int h = blockIdx.y;
  const int side = lane >> 5, hl = lane & 31;
  const int Dh = D >> 1;

  jl[wave][lane] = ell[(size_t)i * ELL_STRIDE + lane];
  jl[wave][64 + lane] = ell[(size_t)i * ELL_STRIDE + 64 + lane];
  const int dc = degcnt[i];
  const int d = dc < ELL_STRIDE ? dc : ELL_STRIDE;
  const int kmax = (d + 1) & ~1;  // pads (zero row) cover odd d

  const unsigned short* __restrict__ hb = Hs + h * Dh + hl * 8;
  float acc[8] = {0.f, 0.f, 0.f, 0.f, 0.f, 0.f, 0.f, 0.f};

  {  // self term once: side 0 -> row i, side 1 -> zero pad row
    const int js = side ? n : i;
    const uint4 hv = *(const uint4*)(hb + (size_t)js * D);
    acc[0] += bflo(hv.x); acc[1] += bfhi(hv.x);
    acc[2] += bflo(hv.y); acc[3] += bfhi(hv.y);
    acc[4] += bflo(hv.z); acc[5] += bfhi(hv.z);
    acc[6] += bflo(hv.w); acc[7] += bfhi(hv.w);
  }
#pragma unroll 8
  for (int k = 0; k < kmax; k += 2) {
    const int j = jl[wave][k + side];  // 2 addrs in one LDS word: conflict-free
    const uint4 hv = *(const uint4*)(hb + (size_t)j * D);
    acc[0] += bflo(hv.x); acc[1] += bfhi(hv.x);
    acc[2] += bflo(hv.y); acc[3] += bfhi(hv.y);
    acc[4] += bflo(hv.z); acc[5] += bfhi(hv.z);
    acc[6] += bflo(hv.w); acc[7] += bfhi(hv.w);
  }
#pragma unroll
  for (int t = 0; t < 8; ++t) acc[t] += __shfl_xor(acc[t], 32, 64);

  if (side == 0) {
    const float di = rsqrtf((float)dc + 1.0f);
    const float4 b0 = *(const float4*)(bias + h * Dh + hl * 8);
    const float4 b1 = *(const float4*)(bias + h * Dh + hl * 8 + 4);
    float* op = out + (size_t)i * D + h * Dh + hl * 8;
    float4 o0, o1;
    o0.x = di * acc[0] + b0.x; o0.y = di * acc[1] + b0.y;
    o0.z = di * acc[2] + b0.z; o0.w = di * acc[3] + b0.w;
    o1.x = di * acc[4] + b1.x; o1.y = di * acc[5] + b1.y;
    o1.z = di * acc[6] + b1.z; o1.w = di * acc[7] + b1.w;
    *(float4*)op = o0;
    *(float4*)(op + 4) = o1;
  }
}

extern "C" void kernel_launch(void* const* d_in, const int* in_sizes, int n_in,
                              void* d_out, int out_size, void* d_ws, size_t ws_size,
                              hipStream_t stream) {
  const float* x    = (const float*)d_in[0];
  const int*   ei   = (const int*)d_in[1];
  const float* W    = (const float*)d_in[2];
  const float* bias = (const float*)d_in[3];
  float* out = (float*)d_out;

  const int d_out_dim = in_sizes[3];             // 512
  const int d_in_dim  = in_sizes[2] / d_out_dim; // 512
  const int n_nodes   = in_sizes[0] / d_in_dim;  // 8192
  const int n_edges   = in_sizes[1] / 2;         // 262144
  const int words     = (n_nodes + 31) / 32;     // 256

  // workspace layout (bytes); mask+degcnt contiguous for one memset
  char* ws = (char*)d_ws;
  size_t off = 0;
  unsigned* mask = (unsigned*)(ws + off); off += (size_t)n_nodes * words * 4;       // 8 MB
  int* degcnt    = (int*)(ws + off);      off += (size_t)n_nodes * 4;               // 32 KB
  unsigned short* ell = (unsigned short*)(ws + off); off += (size_t)n_nodes * ELL_STRIDE * 2; // 2 MB
  unsigned short* xb  = (unsigned short*)(ws + off); off += (size_t)n_nodes * d_in_dim * 2;   // 8 MB
  unsigned short* Wt  = (unsigned short*)(ws + off); off += (size_t)d_in_dim * d_out_dim * 2; // 512 KB
  unsigned short* Hs  = (unsigned short*)(ws + off);
  off += (size_t)(n_nodes + 1) * d_out_dim * 2;  // 8 MB + pad row

  hipMemsetAsync(mask, 0, (size_t)n_nodes * words * 4 + (size_t)n_nodes * 4, stream);

  const int edge_blocks = (n_edges + 255) / 256;              // 1024
  const int n4 = n_nodes * d_in_dim / 4;
  const int cast_blocks = (n4 + 255) / 256;                   // 4096
  const int tr_blocks = (d_in_dim / 32) * (d_out_dim / 32);   // 256
  fused_front_kernel<<<edge_blocks + cast_blocks + tr_blocks + 1, 256, 0, stream>>>(
      ei, mask, degcnt, n_edges, words, x, xb, n4, W, Wt, d_in_dim, d_out_dim,
      Hs, n_nodes, edge_blocks, cast_blocks, tr_blocks);

  const int nbx = d_out_dim / 64;                             // 8
  const int nbx_sh = 31 - __builtin_clz(nbx);                 // 3
  const int gemm_blocks = nbx * (n_nodes / 64);               // 1024
  const int ell_blocks = n_nodes / 4;                         // 2048
  fused_mid_kernel<<<gemm_blocks + ell_blocks, 256, 0, stream>>>(
      xb, Wt, degcnt, Hs, mask, ell,
      n_nodes, d_out_dim, d_in_dim, words, gemm_blocks, nbx_sh);

  dim3 sgrid(n_nodes / 4, 2);
  spmm_kernel<<<sgrid, 256, 0, stream>>>(ell, degcnt, Hs, bias, out,
                                         n_nodes, d_out_dim);
}

// Round 8
// 160.955 us; speedup vs baseline: 1.0436x; 1.0436x over previous
//
#include <hip/hip_runtime.h>
#include <hip/hip_bf16.h>

// ---------------------------------------------------------------------------
// GCN layer: out = D^{-1/2} (A_set + I) D^{-1/2} @ (x @ W) + bias
// Pipeline (4 dispatches):
//   memset mask (8MB)
//   fused_front: [build_adj (fire-and-forget atomicOr bitmask)
//                 | cast x->bf16 | transpose W | zero Hs pad row]
//     - cross-workgroup writes MUST be atomics (round-4 lesson)
//     - NO returned atomics (round-7 lesson: blocking on the atomic's old
//       value costs a ~900cyc round trip per edge -> 52us front)
//   fused_mid: [gemm 64x64 MFMA: Hs = bf16(x@W)  (UNSCALED -> no dinv dep)
//               | build_ell: mask -> ELL list + deg + dinv]
//     - block-range fused: ell (memory-bound) overlaps gemm (MFMA-bound)
//   spmm: D-split (grid.y=2 halves, 4MB hot set = L2-resident per half);
//     half-wave per neighbor (2/iter, 16B/lane); per-neighbor dinv[j] scale
//     (broadcast 4B load, L1-resident 32KB table);
//     out[i] = dinv_i*(dinv_i*H_i + sum_j dinv_j*H_j) + bias
// ---------------------------------------------------------------------------

#define ELL_STRIDE 128

typedef __attribute__((ext_vector_type(8))) short bf16x8;
typedef __attribute__((ext_vector_type(4))) float f32x4;

__device__ __forceinline__ unsigned short f2bf(float f) {
  unsigned u = __float_as_uint(f);
  u = (u + 0x7fff + ((u >> 16) & 1)) >> 16;  // RNE
  return (unsigned short)u;
}
__device__ __forceinline__ float bflo(unsigned u) {
  return __uint_as_float(u << 16);
}
__device__ __forceinline__ float bfhi(unsigned u) {
  return __uint_as_float(u & 0xffff0000u);
}

// ---- fused front-end:
// [0,eb): build_adj  [eb,eb+cb): cast  [..+tb): transpose  [last]: zero pad row
__global__ __launch_bounds__(256) void fused_front_kernel(
    const int* __restrict__ ei, unsigned* __restrict__ mask, int n_edges,
    int words,
    const float* __restrict__ x, unsigned short* __restrict__ xb, int n4,
    const float* __restrict__ W, unsigned short* __restrict__ Wt, int K, int N,
    unsigned short* __restrict__ Hs, int n_nodes,
    int edge_blocks, int cast_blocks, int tr_blocks) {
  const int bid = blockIdx.x;
  if (bid < edge_blocks) {
    const int e = bid * 256 + threadIdx.x;
    if (e < n_edges) {
      const int u = ei[e];
      const int v = ei[e + n_edges];
      // fire-and-forget: no use of the return value (round-7 lesson)
      atomicOr(&mask[(size_t)u * words + (v >> 5)], 1u << (v & 31));
      atomicOr(&mask[(size_t)v * words + (u >> 5)], 1u << (u & 31));
    }
    return;
  }
  if (bid < edge_blocks + cast_blocks) {
    const int t = (bid - edge_blocks) * 256 + threadIdx.x;
    if (t < n4) {
      float4 v = ((const float4*)x)[t];
      ushort4 o;
      o.x = f2bf(v.x); o.y = f2bf(v.y); o.z = f2bf(v.z); o.w = f2bf(v.w);
      ((ushort4*)xb)[t] = o;
    }
    return;
  }
  if (bid < edge_blocks + cast_blocks + tr_blocks) {
    // transpose+cast: W[K][N] fp32 -> Wt[N][K] bf16, 32x32 tiles
    __shared__ float tile[32][33];
    const int b = bid - edge_blocks - cast_blocks;
    const int bx = b & ((N >> 5) - 1);
    const int by = b >> (31 - __builtin_clz(N >> 5));
    const int tx = threadIdx.x & 31;
    const int ty = threadIdx.x >> 5;  // 0..7
#pragma unroll
    for (int r = 0; r < 4; ++r)
      tile[ty + 8 * r][tx] = W[(size_t)(by * 32 + ty + 8 * r) * N + bx * 32 + tx];
    __syncthreads();
#pragma unroll
    for (int r = 0; r < 4; ++r)
      Wt[(size_t)(bx * 32 + ty + 8 * r) * K + by * 32 + tx] =
          f2bf(tile[tx][ty + 8 * r]);
    return;
  }
  // zero the ELL pad row Hs[n_nodes][:]  (N bf16 = N/2 uints)
  {
    const int t = threadIdx.x;
    if (t < (N >> 1)) ((unsigned*)(Hs + (size_t)n_nodes * N))[t] = 0;
  }
}

// ---- fused mid: [0,gb): gemm 64x64   [gb..): build_ell (wave per node)
__global__ __launch_bounds__(256) void fused_mid_kernel(
    const unsigned short* __restrict__ xb,  // [M][K] bf16
    const unsigned short* __restrict__ Wt,  // [N][K] bf16
    unsigned short* __restrict__ Hs,        // [M+1][N] bf16 (unscaled)
    const unsigned* __restrict__ mask, unsigned short* __restrict__ ell,
    int* __restrict__ deg, float* __restrict__ dinv,
    int M, int N, int K, int words, int gemm_blocks, int nbx_sh) {
  __shared__ unsigned short As[256 * 8];
  __shared__ unsigned short Bs[256 * 8];

  const int tid = threadIdx.x;
  const int bid = blockIdx.x;

  if (bid < gemm_blocks) {
    if (bid == 0 && tid == 0) dinv[M] = 0.f;  // pad-row scale (see spmm)
    const int wave = tid >> 6;
    const int lane = tid & 63;
    const int q = lane >> 4;   // quad
    const int c = lane & 15;
    const int bx = bid & ((1 << nbx_sh) - 1);
    const int by = bid >> nbx_sh;
    const int m0 = by * 64;
    const int n0 = bx * 64;
    const int wr = wave >> 1, wc = wave & 1;

    f32x4 acc[2][2] = {};

    for (int k0 = 0; k0 < K; k0 += 32) {
      {
        const unsigned short* g =
            xb + (size_t)(m0 + lane) * K + k0 + wave * 8;  // kc=wave, row=lane
        __builtin_amdgcn_global_load_lds(
            (const __attribute__((address_space(1))) void*)g,
            (__attribute__((address_space(3))) void*)(As + wave * 64 * 8), 16, 0, 0);
      }
      {
        const int s = tid;  // B: n = s>>2, kc = s&3
        const unsigned short* g =
            Wt + (size_t)(n0 + (s >> 2)) * K + k0 + (s & 3) * 8;
        __builtin_amdgcn_global_load_lds(
            (const __attribute__((address_space(1))) void*)g,
            (__attribute__((address_space(3))) void*)(Bs + wave * 64 * 8), 16, 0, 0);
      }
      __syncthreads();

      bf16x8 a[2], b[2];
#pragma unroll
      for (int tm = 0; tm < 2; ++tm) {
        const int row = wr * 32 + tm * 16 + c;
        a[tm] = *(const bf16x8*)(As + (q * 64 + row) * 8);
      }
#pragma unroll
      for (int tn = 0; tn < 2; ++tn) {
        const int n = wc * 32 + tn * 16 + c;
        b[tn] = *(const bf16x8*)(Bs + (n * 4 + q) * 8);
      }
#pragma unroll
      for (int tm = 0; tm < 2; ++tm)
#pragma unroll
        for (int tn = 0; tn < 2; ++tn)
          acc[tm][tn] = __builtin_amdgcn_mfma_f32_16x16x32_bf16(
              a[tm], b[tn], acc[tm][tn], 0, 0, 0);
      __syncthreads();
    }

    // C/D mapping: col=lane&15, row=quad*4+reg ; NO scale here
#pragma unroll
    for (int tm = 0; tm < 2; ++tm) {
#pragma unroll
      for (int r = 0; r < 4; ++r) {
        const int grow = m0 + wr * 32 + tm * 16 + q * 4 + r;
#pragma unroll
        for (int tn = 0; tn < 2; ++tn) {
          const int gcol = n0 + wc * 32 + tn * 16 + c;
          Hs[(size_t)grow * N + gcol] = f2bf(acc[tm][tn][r]);
        }
      }
    }
    return;
  }

  // ---- build_ell: one wave per node, popcount + lane prefix-scan
  {
    const int wave = tid >> 6, lane = tid & 63;
    const int node = (bid - gemm_blocks) * 4 + wave;
    const unsigned* __restrict__ row = mask + (size_t)node * words;
    unsigned short* __restrict__ out = ell + (size_t)node * ELL_STRIDE;

    int running = 0;
    for (int r = 0; r < words; r += 64) {
      const int w = r + lane;
      unsigned bits = row[w];
      const int cnt = __popc(bits);
      int x = cnt;
#pragma unroll
      for (int d = 1; d < 64; d <<= 1) {
        int y = __shfl_up(x, d, 64);
        if (lane >= d) x += y;
      }
      int pos = running + x - cnt;
      while (bits) {
        const int b = __builtin_ctz(bits);
        bits &= bits - 1;
        if (pos < ELL_STRIDE) out[pos] = (unsigned short)((w << 5) + b);
        ++pos;
      }
      running += __shfl(x, 63, 64);
    }
    if (lane == 0) {
      const int dd = running < ELL_STRIDE ? running : ELL_STRIDE;
      deg[node] = dd;
      dinv[node] = rsqrtf((float)running + 1.0f);
      // pad to even count with the zero row (index M) for the pair-gather
      if (running < ELL_STRIDE) out[running] = (unsigned short)M;
      if (running + 1 < ELL_STRIDE) out[running + 1] = (unsigned short)M;
    }
  }
}

// ---- spmm: grid (n/4, 2). Half h covers columns [h*D/2, (h+1)*D/2).
// Wave = one node; half-wave per neighbor (2/iter, 16B/lane); per-neighbor
// dinv[j] scale; shfl_xor(32) cross-half reduce. 4MB hot set per half.
__global__ __launch_bounds__(256) void spmm_kernel(
    const unsigned short* __restrict__ ell, const int* __restrict__ deg,
    const float* __restrict__ dinv, const unsigned short* __restrict__ Hs,
    const float* __restrict__ bias, float* __restrict__ out, int n, int D) {
  __shared__ unsigned short jl[4][ELL_STRIDE];
  const int wave = threadIdx.x >> 6, lane = threadIdx.x & 63;
  const int i = blockIdx.x * 4 + wave;  // n divisible by 4
  const int h = blockIdx.y;
  const int side = lane >> 5, hl = lane & 31;
  const int Dh = D >> 1;

  jl[wave][lane] = ell[(size_t)i * ELL_STRIDE + lane];
  jl[wave][64 + lane] = ell[(size_t)i * ELL_STRIDE + 64 + lane];
  const int d = deg[i];
  const float di = dinv[i];
  const int kmax = (d + 1) & ~1;  // pads (zero row) cover odd d

  const unsigned short* __restrict__ hb = Hs + h * Dh + hl * 8;
  float acc[8] = {0.f, 0.f, 0.f, 0.f, 0.f, 0.f, 0.f, 0.f};

  {  // self term: side 0 -> dinv_i * H_i, side 1 -> 0 * pad row
    const int js = side ? n : i;
    const float ds = side ? 0.f : di;
    const uint4 hv = *(const uint4*)(hb + (size_t)js * D);
    acc[0] += ds * bflo(hv.x); acc[1] += ds * bfhi(hv.x);
    acc[2] += ds * bflo(hv.y); acc[3] += ds * bfhi(hv.y);
    acc[4] += ds * bflo(hv.z); acc[5] += ds * bfhi(hv.z);
    acc[6] += ds * bflo(hv.w); acc[7] += ds * bfhi(hv.w);
  }
#pragma unroll 8
  for (int k = 0; k < kmax; k += 2) {
    const int j = jl[wave][k + side];  // 2 addrs in one LDS word
    const float dj = dinv[j];          // broadcast 4B, L1-resident table
    const uint4 hv = *(const uint4*)(hb + (size_t)j * D);
    acc[0] += dj * bflo(hv.x); acc[1] += dj * bfhi(hv.x);
    acc[2] += dj * bflo(hv.y); acc[3] += dj * bfhi(hv.y);
    acc[4] += dj * bflo(hv.z); acc[5] += dj * bfhi(hv.z);
    acc[6] += dj * bflo(hv.w); acc[7] += dj * bfhi(hv.w);
  }
#pragma unroll
  for (int t = 0; t < 8; ++t) acc[t] += __shfl_xor(acc[t], 32, 64);

  if (side == 0) {
    const float4 b0 = *(const float4*)(bias + h * Dh + hl * 8);
    const float4 b1 = *(const float4*)(bias + h * Dh + hl * 8 + 4);
    float* op = out + (size_t)i * D + h * Dh + hl * 8;
    float4 o0, o1;
    o0.x = di * acc[0] + b0.x; o0.y = di * acc[1] + b0.y;
    o0.z = di * acc[2] + b0.z; o0.w = di * acc[3] + b0.w;
    o1.x = di * acc[4] + b1.x; o1.y = di * acc[5] + b1.y;
    o1.z = di * acc[6] + b1.z; o1.w = di * acc[7] + b1.w;
    *(float4*)op = o0;
    *(float4*)(op + 4) = o1;
  }
}

extern "C" void kernel_launch(void* const* d_in, const int* in_sizes, int n_in,
                              void* d_out, int out_size, void* d_ws, size_t ws_size,
                              hipStream_t stream) {
  const float* x    = (const float*)d_in[0];
  const int*   ei   = (const int*)d_in[1];
  const float* W    = (const float*)d_in[2];
  const float* bias = (const float*)d_in[3];
  float* out = (float*)d_out;

  const int d_out_dim = in_sizes[3];             // 512
  const int d_in_dim  = in_sizes[2] / d_out_dim; // 512
  const int n_nodes   = in_sizes[0] / d_in_dim;  // 8192
  const int n_edges   = in_sizes[1] / 2;         // 262144
  const int words     = (n_nodes + 31) / 32;     // 256

  // workspace layout (bytes)
  char* ws = (char*)d_ws;
  size_t off = 0;
  unsigned* mask = (unsigned*)(ws + off); off += (size_t)n_nodes * words * 4;       // 8 MB
  int* deg       = (int*)(ws + off);      off += (size_t)n_nodes * 4;               // 32 KB
  float* dinv    = (float*)(ws + off);    off += (size_t)(n_nodes + 1) * 4;         // 32 KB + pad
  unsigned short* ell = (unsigned short*)(ws + off); off += (size_t)n_nodes * ELL_STRIDE * 2; // 2 MB
  unsigned short* xb  = (unsigned short*)(ws + off); off += (size_t)n_nodes * d_in_dim * 2;   // 8 MB
  unsigned short* Wt  = (unsigned short*)(ws + off); off += (size_t)d_in_dim * d_out_dim * 2; // 512 KB
  unsigned short* Hs  = (unsigned short*)(ws + off);
  off += (size_t)(n_nodes + 1) * d_out_dim * 2;  // 8 MB + pad row

  hipMemsetAsync(mask, 0, (size_t)n_nodes * words * 4, stream);

  const int edge_blocks = (n_edges + 255) / 256;              // 1024
  const int n4 = n_nodes * d_in_dim / 4;
  const int cast_blocks = (n4 + 255) / 256;                   // 4096
  const int tr_blocks = (d_in_dim / 32) * (d_out_dim / 32);   // 256
  fused_front_kernel<<<edge_blocks + cast_blocks + tr_blocks + 1, 256, 0, stream>>>(
      ei, mask, n_edges, words, x, xb, n4, W, Wt, d_in_dim, d_out_dim,
      Hs, n_nodes, edge_blocks, cast_blocks, tr_blocks);

  const int nbx = d_out_dim / 64;                             // 8
  const int nbx_sh = 31 - __builtin_clz(nbx);                 // 3
  const int gemm_blocks = nbx * (n_nodes / 64);               // 1024
  const int ell_blocks = n_nodes / 4;                         // 2048
  fused_mid_kernel<<<gemm_blocks + ell_blocks, 256, 0, stream>>>(
      xb, Wt, Hs, mask, ell, deg, dinv,
      n_nodes, d_out_dim, d_in_dim, words, gemm_blocks, nbx_sh);

  dim3 sgrid(n_nodes / 4, 2);
  spmm_kernel<<<sgrid, 256, 0, stream>>>(ell, deg, dinv, Hs, bias, out,
                                         n_nodes, d_out_dim);
}

// Round 9
// 156.795 us; speedup vs baseline: 1.0713x; 1.0265x over previous
//
#include <hip/hip_runtime.h>
#include <hip/hip_bf16.h>

// ---------------------------------------------------------------------------
// GCN layer: out = D^{-1/2} (A_set + I) D^{-1/2} @ (x @ W) + bias
// Pipeline (4 dispatches):
//   memset mask (8MB)
//   fused_front: [build_adj (fire-and-forget atomicOr bitmask)
//                 | cast x->bf16 | transpose W | zero Hs pad row + dinv[M]]
//     - cross-workgroup writes MUST be atomics (round-4 lesson)
//     - NO returned atomics (round-7 lesson: ~900cyc blocking round trip)
//   fused_mid: [gemm 64x64 MFMA BK=64: Hs = bf16(x@W) (unscaled, no dinv dep)
//               | build_ell: mask -> ELL list (+self entry, zero-row pads)
//                            + deg + dinv]
//   spmm: D-split (grid.y=2 halves); (j, dinv[j]) staged as packed uint2 in
//     LDS once per wave (round-8 lesson: per-iter global dinv load sat on the
//     gather critical path); self term is just another ELL entry;
//     out[i] = dinv_i * sum_{j in ell(i)} dinv_j*H_j + bias
// ---------------------------------------------------------------------------

#define ELL_STRIDE 128

typedef __attribute__((ext_vector_type(8))) short bf16x8;
typedef __attribute__((ext_vector_type(4))) float f32x4;

__device__ __forceinline__ unsigned short f2bf(float f) {
  unsigned u = __float_as_uint(f);
  u = (u + 0x7fff + ((u >> 16) & 1)) >> 16;  // RNE
  return (unsigned short)u;
}
__device__ __forceinline__ float bflo(unsigned u) {
  return __uint_as_float(u << 16);
}
__device__ __forceinline__ float bfhi(unsigned u) {
  return __uint_as_float(u & 0xffff0000u);
}

// ---- fused front-end:
// [0,eb): build_adj  [eb,eb+cb): cast  [..+tb): transpose  [last]: pad row
__global__ __launch_bounds__(256) void fused_front_kernel(
    const int* __restrict__ ei, unsigned* __restrict__ mask, int n_edges,
    int words,
    const float* __restrict__ x, unsigned short* __restrict__ xb, int n4,
    const float* __restrict__ W, unsigned short* __restrict__ Wt, int K, int N,
    unsigned short* __restrict__ Hs, float* __restrict__ dinv, int n_nodes,
    int edge_blocks, int cast_blocks, int tr_blocks) {
  const int bid = blockIdx.x;
  if (bid < edge_blocks) {
    const int e = bid * 256 + threadIdx.x;
    if (e < n_edges) {
      const int u = ei[e];
      const int v = ei[e + n_edges];
      // fire-and-forget: never use the return value (round-7 lesson)
      atomicOr(&mask[(size_t)u * words + (v >> 5)], 1u << (v & 31));
      atomicOr(&mask[(size_t)v * words + (u >> 5)], 1u << (u & 31));
    }
    return;
  }
  if (bid < edge_blocks + cast_blocks) {
    const int t = (bid - edge_blocks) * 256 + threadIdx.x;
    if (t < n4) {
      float4 v = ((const float4*)x)[t];
      ushort4 o;
      o.x = f2bf(v.x); o.y = f2bf(v.y); o.z = f2bf(v.z); o.w = f2bf(v.w);
      ((ushort4*)xb)[t] = o;
    }
    return;
  }
  if (bid < edge_blocks + cast_blocks + tr_blocks) {
    // transpose+cast: W[K][N] fp32 -> Wt[N][K] bf16, 32x32 tiles
    __shared__ float tile[32][33];
    const int b = bid - edge_blocks - cast_blocks;
    const int bx = b & ((N >> 5) - 1);
    const int by = b >> (31 - __builtin_clz(N >> 5));
    const int tx = threadIdx.x & 31;
    const int ty = threadIdx.x >> 5;  // 0..7
#pragma unroll
    for (int r = 0; r < 4; ++r)
      tile[ty + 8 * r][tx] = W[(size_t)(by * 32 + ty + 8 * r) * N + bx * 32 + tx];
    __syncthreads();
#pragma unroll
    for (int r = 0; r < 4; ++r)
      Wt[(size_t)(bx * 32 + ty + 8 * r) * K + by * 32 + tx] =
          f2bf(tile[tx][ty + 8 * r]);
    return;
  }
  // zero the ELL pad row Hs[n_nodes][:] and its scale dinv[n_nodes]
  {
    const int t = threadIdx.x;
    if (t < (N >> 1)) ((unsigned*)(Hs + (size_t)n_nodes * N))[t] = 0;
    if (t == 0) dinv[n_nodes] = 0.f;
  }
}

// ---- fused mid: [0,gb): gemm 64x64 BK=64   [gb..): build_ell (wave/node)
__global__ __launch_bounds__(256) void fused_mid_kernel(
    const unsigned short* __restrict__ xb,  // [M][K] bf16
    const unsigned short* __restrict__ Wt,  // [N][K] bf16
    unsigned short* __restrict__ Hs,        // [M+1][N] bf16 (unscaled)
    const unsigned* __restrict__ mask, unsigned short* __restrict__ ell,
    int* __restrict__ deg, float* __restrict__ dinv,
    int M, int N, int K, int words, int gemm_blocks, int nbx_sh) {
  // A slot s: kc=s>>6 (8B k-chunk), row=s&63 -> xb[m0+row][k0+kc*8]
  // B slot s: n=s>>3, kc=s&7              -> Wt[n0+n][k0+kc*8]
  __shared__ unsigned short As[512 * 8];
  __shared__ unsigned short Bs[512 * 8];

  const int tid = threadIdx.x;
  const int bid = blockIdx.x;

  if (bid < gemm_blocks) {
    const int wave = tid >> 6;
    const int lane = tid & 63;
    const int q = lane >> 4;   // quad
    const int c = lane & 15;
    const int bx = bid & ((1 << nbx_sh) - 1);
    const int by = bid >> nbx_sh;
    const int m0 = by * 64;
    const int n0 = bx * 64;
    const int wr = wave >> 1, wc = wave & 1;

    f32x4 acc[2][2] = {};

    for (int k0 = 0; k0 < K; k0 += 64) {
#pragma unroll
      for (int t = 0; t < 2; ++t) {
        const int sbase = t * 256 + wave * 64;
        const int s = sbase + lane;
        const unsigned short* g =
            xb + (size_t)(m0 + (s & 63)) * K + k0 + (s >> 6) * 8;
        __builtin_amdgcn_global_load_lds(
            (const __attribute__((address_space(1))) void*)g,
            (__attribute__((address_space(3))) void*)(As + sbase * 8), 16, 0, 0);
      }
#pragma unroll
      for (int t = 0; t < 2; ++t) {
        const int sbase = t * 256 + wave * 64;
        const int s = sbase + lane;
        const unsigned short* g =
            Wt + (size_t)(n0 + (s >> 3)) * K + k0 + (s & 7) * 8;
        __builtin_amdgcn_global_load_lds(
            (const __attribute__((address_space(1))) void*)g,
            (__attribute__((address_space(3))) void*)(Bs + sbase * 8), 16, 0, 0);
      }
      __syncthreads();

#pragma unroll
      for (int kk = 0; kk < 2; ++kk) {
        bf16x8 a[2], b[2];
#pragma unroll
        for (int tm = 0; tm < 2; ++tm) {
          const int row = wr * 32 + tm * 16 + c;
          a[tm] = *(const bf16x8*)(As + (((kk * 4 + q) * 64) + row) * 8);
        }
#pragma unroll
        for (int tn = 0; tn < 2; ++tn) {
          const int n = wc * 32 + tn * 16 + c;
          b[tn] = *(const bf16x8*)(Bs + (n * 8 + kk * 4 + q) * 8);
        }
#pragma unroll
        for (int tm = 0; tm < 2; ++tm)
#pragma unroll
          for (int tn = 0; tn < 2; ++tn)
            acc[tm][tn] = __builtin_amdgcn_mfma_f32_16x16x32_bf16(
                a[tm], b[tn], acc[tm][tn], 0, 0, 0);
      }
      __syncthreads();
    }

    // C/D mapping: col=lane&15, row=quad*4+reg ; unscaled store
#pragma unroll
    for (int tm = 0; tm < 2; ++tm) {
#pragma unroll
      for (int r = 0; r < 4; ++r) {
        const int grow = m0 + wr * 32 + tm * 16 + q * 4 + r;
#pragma unroll
        for (int tn = 0; tn < 2; ++tn) {
          const int gcol = n0 + wc * 32 + tn * 16 + c;
          Hs[(size_t)grow * N + gcol] = f2bf(acc[tm][tn][r]);
        }
      }
    }
    return;
  }

  // ---- build_ell: one wave per node, popcount + lane prefix-scan.
  // Emits distinct neighbors, then THE NODE ITSELF (self term: scale dinv_i
  // matches the spmm loop body), then zero-row pads to fill the stride
  // (poison-safe staged dinv reads in spmm).
  {
    const int wave = tid >> 6, lane = tid & 63;
    const int node = (bid - gemm_blocks) * 4 + wave;
    const unsigned* __restrict__ row = mask + (size_t)node * words;
    unsigned short* __restrict__ out = ell + (size_t)node * ELL_STRIDE;

    int running = 0;
    for (int r = 0; r < words; r += 64) {
      const int w = r + lane;
      unsigned bits = row[w];
      const int cnt = __popc(bits);
      int x = cnt;
#pragma unroll
      for (int d = 1; d < 64; d <<= 1) {
        int y = __shfl_up(x, d, 64);
        if (lane >= d) x += y;
      }
      int pos = running + x - cnt;
      while (bits) {
        const int b = __builtin_ctz(bits);
        bits &= bits - 1;
        if (pos < ELL_STRIDE) out[pos] = (unsigned short)((w << 5) + b);
        ++pos;
      }
      running += __shfl(x, 63, 64);
    }
    // self entry at [running], pads (index M -> dinv 0, zero row) after
    for (int p = running + lane; p < ELL_STRIDE; p += 64)
      out[p] = (unsigned short)(p == running ? node : M);
    if (lane == 0) {
      const int dd = running + 1;  // + self
      deg[node] = dd < ELL_STRIDE ? dd : ELL_STRIDE;
      dinv[node] = rsqrtf((float)running + 1.0f);
    }
  }
}

// ---- spmm: grid (n/4, 2). Half h covers columns [h*D/2, (h+1)*D/2).
// Wave = one node; half-wave per entry (2/iter, 16B/lane). (j, dinv[j])
// staged once per wave as packed uint2 in LDS -> one ds_read_b64 per iter,
// no global loads on the gather critical path. shfl_xor(32) reduce.
__global__ __launch_bounds__(256) void spmm_kernel(
    const unsigned short* __restrict__ ell, const int* __restrict__ deg,
    const float* __restrict__ dinv, const unsigned short* __restrict__ Hs,
    const float* __restrict__ bias, float* __restrict__ out, int n, int D) {
  __shared__ uint2 ji[4][ELL_STRIDE];
  const int wave = threadIdx.x >> 6, lane = threadIdx.x & 63;
  const int i = blockIdx.x * 4 + wave;  // n divisible by 4
  const int h = blockIdx.y;
  const int side = lane >> 5, hl = lane & 31;
  const int Dh = D >> 1;

  {  // stage (j, dinv[j]) — 2 entries per lane, scattered loads pipelined
    const unsigned j0 = ell[(size_t)i * ELL_STRIDE + lane];
    const unsigned j1 = ell[(size_t)i * ELL_STRIDE + 64 + lane];
    ji[wave][lane] = make_uint2(j0, __float_as_uint(dinv[j0]));
    ji[wave][64 + lane] = make_uint2(j1, __float_as_uint(dinv[j1]));
  }
  const int d = deg[i];          // includes the self entry
  const float di = dinv[i];
  const int kmax = (d + 1) & ~1; // pads (dinv 0, zero row) cover odd d

  const unsigned short* __restrict__ hb = Hs + h * Dh + hl * 8;
  float acc[8] = {0.f, 0.f, 0.f, 0.f, 0.f, 0.f, 0.f, 0.f};

#pragma unroll 8
  for (int k = 0; k < kmax; k += 2) {
    const uint2 e = ji[wave][k + side];  // 2 addrs/wave: broadcast, no conflict
    const int j = e.x;
    const float dj = __uint_as_float(e.y);
    const uint4 hv = *(const uint4*)(hb + (size_t)j * D);
    acc[0] += dj * bflo(hv.x); acc[1] += dj * bfhi(hv.x);
    acc[2] += dj * bflo(hv.y); acc[3] += dj * bfhi(hv.y);
    acc[4] += dj * bflo(hv.z); acc[5] += dj * bfhi(hv.z);
    acc[6] += dj * bflo(hv.w); acc[7] += dj * bfhi(hv.w);
  }
#pragma unroll
  for (int t = 0; t < 8; ++t) acc[t] += __shfl_xor(acc[t], 32, 64);

  if (side == 0) {
    const float4 b0 = *(const float4*)(bias + h * Dh + hl * 8);
    const float4 b1 = *(const float4*)(bias + h * Dh + hl * 8 + 4);
    float* op = out + (size_t)i * D + h * Dh + hl * 8;
    float4 o0, o1;
    o0.x = di * acc[0] + b0.x; o0.y = di * acc[1] + b0.y;
    o0.z = di * acc[2] + b0.z; o0.w = di * acc[3] + b0.w;
    o1.x = di * acc[4] + b1.x; o1.y = di * acc[5] + b1.y;
    o1.z = di * acc[6] + b1.z; o1.w = di * acc[7] + b1.w;
    *(float4*)op = o0;
    *(float4*)(op + 4) = o1;
  }
}

extern "C" void kernel_launch(void* const* d_in, const int* in_sizes, int n_in,
                              void* d_out, int out_size, void* d_ws, size_t ws_size,
                              hipStream_t stream) {
  const float* x    = (const float*)d_in[0];
  const int*   ei   = (const int*)d_in[1];
  const float* W    = (const float*)d_in[2];
  const float* bias = (const float*)d_in[3];
  float* out = (float*)d_out;

  const int d_out_dim = in_sizes[3];             // 512
  const int d_in_dim  = in_sizes[2] / d_out_dim; // 512
  const int n_nodes   = in_sizes[0] / d_in_dim;  // 8192
  const int n_edges   = in_sizes[1] / 2;         // 262144
  const int words     = (n_nodes + 31) / 32;     // 256

  // workspace layout (bytes)
  char* ws = (char*)d_ws;
  size_t off = 0;
  unsigned* mask = (unsigned*)(ws + off); off += (size_t)n_nodes * words * 4;       // 8 MB
  int* deg       = (int*)(ws + off);      off += (size_t)n_nodes * 4;               // 32 KB
  float* dinv    = (float*)(ws + off);    off += (size_t)(n_nodes + 1) * 4;         // 32 KB + pad
  unsigned short* ell = (unsigned short*)(ws + off); off += (size_t)n_nodes * ELL_STRIDE * 2; // 2 MB
  unsigned short* xb  = (unsigned short*)(ws + off); off += (size_t)n_nodes * d_in_dim * 2;   // 8 MB
  unsigned short* Wt  = (unsigned short*)(ws + off); off += (size_t)d_in_dim * d_out_dim * 2; // 512 KB
  unsigned short* Hs  = (unsigned short*)(ws + off);
  off += (size_t)(n_nodes + 1) * d_out_dim * 2;  // 8 MB + pad row

  hipMemsetAsync(mask, 0, (size_t)n_nodes * words * 4, stream);

  const int edge_blocks = (n_edges + 255) / 256;              // 1024
  const int n4 = n_nodes * d_in_dim / 4;
  const int cast_blocks = (n4 + 255) / 256;                   // 4096
  const int tr_blocks = (d_in_dim / 32) * (d_out_dim / 32);   // 256
  fused_front_kernel<<<edge_blocks + cast_blocks + tr_blocks + 1, 256, 0, stream>>>(
      ei, mask, n_edges, words, x, xb, n4, W, Wt, d_in_dim, d_out_dim,
      Hs, dinv, n_nodes, edge_blocks, cast_blocks, tr_blocks);

  const int nbx = d_out_dim / 64;                             // 8
  const int nbx_sh = 31 - __builtin_clz(nbx);                 // 3
  const int gemm_blocks = nbx * (n_nodes / 64);               // 1024
  const int ell_blocks = n_nodes / 4;                         // 2048
  fused_mid_kernel<<<gemm_blocks + ell_blocks, 256, 0, stream>>>(
      xb, Wt, Hs, mask, ell, deg, dinv,
      n_nodes, d_out_dim, d_in_dim, words, gemm_blocks, nbx_sh);

  dim3 sgrid(n_nodes / 4, 2);
  spmm_kernel<<<sgrid, 256, 0, stream>>>(ell, deg, dinv, Hs, bias, out,
                                         n_nodes, d_out_dim);
}